// Round 7
// baseline (1157.509 us; speedup 1.0000x reference)
//
#include <hip/hip_runtime.h>

// Problem constants
#define D_  1024
#define S_  2048
#define B_  4
#define H_  16
#define HD_ 64
#define BS_ (B_*S_)   // 8192 rows

typedef __attribute__((ext_vector_type(8))) short short8;   // 8 bf16 = 4 VGPRs
typedef __attribute__((ext_vector_type(4))) float floatx4;  // MFMA C/D

// Workspace layout (byte offsets), 72 MB total.
#define WS_XB ((size_t)0)            // 16 MB bf16 x
#define WS_WQ ((size_t)16 << 20)     // 2 MB bf16 Wq
#define WS_WK ((size_t)18 << 20)
#define WS_WV ((size_t)20 << 20)
#define WS_WO ((size_t)22 << 20)
#define WS_Q  ((size_t)24 << 20)     // 16 MB bf16 Q [b,h,s,hd]
#define WS_KK ((size_t)40 << 20)     // 16 MB bf16 K [b,h,s,hd]
#define WS_VT ((size_t)56 << 20)     // 16 MB bf16 V^T [b,h,hd,s]
#define WS_Y  WS_Q                   // y (fp32, 32 MB) overlays Q+K after attn

static __device__ __forceinline__ unsigned short f2bf(float f) {
  unsigned u = __builtin_bit_cast(unsigned, f);
  unsigned r = (u + 0x7fffu + ((u >> 16) & 1u)) >> 16;  // RNE
  return (unsigned short)r;
}

// ---------------------------------------------------------------------------
// Kernel 0: fp32 -> bf16 convert (RNE), 4 elements per thread.
// ---------------------------------------------------------------------------
__global__ __launch_bounds__(256) void cvt_f32_bf16(
    const float* __restrict__ src, unsigned short* __restrict__ dst, int n4)
{
  int i = blockIdx.x * 256 + threadIdx.x;
  if (i < n4) {
    float4 v = ((const float4*)src)[i];
    ushort4 o;
    o.x = f2bf(v.x); o.y = f2bf(v.y); o.z = f2bf(v.z); o.w = f2bf(v.w);
    ((ushort4*)dst)[i] = o;
  }
}

// ---------------------------------------------------------------------------
// Kernel 1: QKV projection. C[m,n] = sum_k X[m,k]*W[n,k] + b[n]  (x @ W.T + b)
// mode (blockIdx.z): 0->Q [b,h,s,hd]; 1->K [b,h,s,hd]; 2->V^T [b,h,hd,s].
// ---------------------------------------------------------------------------
__global__ __launch_bounds__(256) void proj_qkv(
    const unsigned short* __restrict__ X,
    const unsigned short* __restrict__ Wq, const float* __restrict__ bq,
    const unsigned short* __restrict__ Wk, const float* __restrict__ bk,
    const unsigned short* __restrict__ Wv, const float* __restrict__ bv,
    unsigned short* __restrict__ Qo, unsigned short* __restrict__ Ko,
    unsigned short* __restrict__ Vo)
{
  const int mode = blockIdx.z;
  const unsigned short* W = (mode == 0) ? Wq : ((mode == 1) ? Wk : Wv);
  const float* bias       = (mode == 0) ? bq : ((mode == 1) ? bk : bv);
  unsigned short* dst     = (mode == 0) ? Qo : ((mode == 1) ? Ko : Vo);

  const int wv   = threadIdx.x >> 6;
  const int lane = threadIdx.x & 63;
  const int c    = lane & 15;
  const int quad = lane >> 4;
  const int m0   = blockIdx.x * 64 + wv * 16;
  const int n0   = blockIdx.y * 64;

  const unsigned short* arow = X + (size_t)(m0 + c) * D_ + quad * 8;
  const unsigned short* brow = W + (size_t)(n0 + c) * D_ + quad * 8;

  floatx4 acc0 = {0.f,0.f,0.f,0.f}, acc1 = {0.f,0.f,0.f,0.f};
  floatx4 acc2 = {0.f,0.f,0.f,0.f}, acc3 = {0.f,0.f,0.f,0.f};

  for (int k0 = 0; k0 < D_; k0 += 32) {
    short8 a  = *(const short8*)(arow + k0);
    short8 b0 = *(const short8*)(brow + k0);
    short8 b1 = *(const short8*)(brow + 16 * D_ + k0);
    short8 b2 = *(const short8*)(brow + 32 * D_ + k0);
    short8 b3 = *(const short8*)(brow + 48 * D_ + k0);
    acc0 = __builtin_amdgcn_mfma_f32_16x16x32_bf16(a, b0, acc0, 0, 0, 0);
    acc1 = __builtin_amdgcn_mfma_f32_16x16x32_bf16(a, b1, acc1, 0, 0, 0);
    acc2 = __builtin_amdgcn_mfma_f32_16x16x32_bf16(a, b2, acc2, 0, 0, 0);
    acc3 = __builtin_amdgcn_mfma_f32_16x16x32_bf16(a, b3, acc3, 0, 0, 0);
  }

  const int b  = m0 >> 11;
  const int s0 = m0 & (S_ - 1);
  const int h  = n0 >> 6;

  floatx4 accs[4] = {acc0, acc1, acc2, acc3};
  #pragma unroll
  for (int j = 0; j < 4; ++j) {
    const int n     = n0 + j * 16 + c;
    const float bv_ = bias[n];
    const int hd    = j * 16 + c;
    if (mode < 2) {
      size_t base = ((size_t)((b * H_ + h) * S_ + s0 + quad * 4)) * HD_ + hd;
      #pragma unroll
      for (int r = 0; r < 4; ++r)
        dst[base + (size_t)r * HD_] = f2bf(accs[j][r] + bv_);
    } else {
      size_t base = ((size_t)((b * H_ + h) * HD_ + hd)) * S_ + s0 + quad * 4;
      #pragma unroll
      for (int r = 0; r < 4; ++r)
        dst[base + r] = f2bf(accs[j][r] + bv_);
    }
  }
}

// ---------------------------------------------------------------------------
// Kernel 2 (v2): flash attention. One wave = 16 q-rows; 64-key tiles;
// NO barriers (per-wave-private LDS slice; in-wave lgkmcnt ordering suffices);
// LDS row padded to 68 floats: writes 2-way (free), b128 reads 16B-aligned.
// ---------------------------------------------------------------------------
__global__ __launch_bounds__(256) void attn_kernel(
    const unsigned short* __restrict__ Q, const unsigned short* __restrict__ K,
    const unsigned short* __restrict__ Vt, const int* __restrict__ mask,
    unsigned short* __restrict__ ctx)
{
  __shared__ float lds_p[4][16][68];   // per-wave P tile (16 q x 64 kp), padded

  const int wv   = threadIdx.x >> 6;
  const int lane = threadIdx.x & 63;
  const int c    = lane & 15;
  const int quad = lane >> 4;

  const int bh = blockIdx.y;
  const int b  = bh >> 4;
  const int h  = bh & 15;
  const int q0 = blockIdx.x * 64 + wv * 16;

  const unsigned short* Qb = Q  + (size_t)bh * S_ * HD_;
  const unsigned short* Kb = K  + (size_t)bh * S_ * HD_;
  const unsigned short* Vb = Vt + (size_t)bh * HD_ * S_;
  const int* mrow = mask + b * S_;

  short8 aQ0 = *(const short8*)(Qb + (size_t)(q0 + c) * HD_ + quad * 8);
  short8 aQ1 = *(const short8*)(Qb + (size_t)(q0 + c) * HD_ + 32 + quad * 8);

  float m_i[4] = {-1e30f, -1e30f, -1e30f, -1e30f};
  float l_i[4] = {0.f, 0.f, 0.f, 0.f};
  floatx4 acc[4];
  #pragma unroll
  for (int d = 0; d < 4; ++d) acc[d] = (floatx4){0.f, 0.f, 0.f, 0.f};

  for (int t = 0; t < S_ / 64; ++t) {
    const int kp0 = t * 64;

    // mask bias per 16-col group
    float mb[4];
    #pragma unroll
    for (int ct = 0; ct < 4; ++ct)
      mb[ct] = (mrow[kp0 + ct * 16 + c] == 0) ? -1e9f : 0.f;

    // QK^T: 4 col-tiles x 2 k-halves = 8 MFMAs
    floatx4 C[4];
    #pragma unroll
    for (int ct = 0; ct < 4; ++ct) {
      const unsigned short* krow = Kb + (size_t)(kp0 + ct * 16 + c) * HD_;
      short8 bK0 = *(const short8*)(krow + quad * 8);
      short8 bK1 = *(const short8*)(krow + 32 + quad * 8);
      floatx4 z = {0.f, 0.f, 0.f, 0.f};
      z = __builtin_amdgcn_mfma_f32_16x16x32_bf16(aQ0, bK0, z, 0, 0, 0);
      z = __builtin_amdgcn_mfma_f32_16x16x32_bf16(aQ1, bK1, z, 0, 0, 0);
      C[ct] = z;
    }

    // scores + row-max
    float s[4][4], tmax[4];
    #pragma unroll
    for (int r = 0; r < 4; ++r) {
      float t0 = C[0][r] * 0.125f + mb[0];
      float t1 = C[1][r] * 0.125f + mb[1];
      float t2 = C[2][r] * 0.125f + mb[2];
      float t3 = C[3][r] * 0.125f + mb[3];
      s[0][r] = t0; s[1][r] = t1; s[2][r] = t2; s[3][r] = t3;
      tmax[r] = fmaxf(fmaxf(t0, t1), fmaxf(t2, t3));
    }
    #pragma unroll
    for (int off = 1; off < 16; off <<= 1) {
      #pragma unroll
      for (int r = 0; r < 4; ++r)
        tmax[r] = fmaxf(tmax[r], __shfl_xor(tmax[r], off, 16));
    }

    // online-softmax update
    float p[4][4], rsum[4], alpha[4];
    #pragma unroll
    for (int r = 0; r < 4; ++r) {
      const float mnew = fmaxf(m_i[r], tmax[r]);
      alpha[r] = __expf(m_i[r] - mnew);
      float r0 = __expf(s[0][r] - mnew);
      float r1 = __expf(s[1][r] - mnew);
      float r2 = __expf(s[2][r] - mnew);
      float r3 = __expf(s[3][r] - mnew);
      p[0][r] = r0; p[1][r] = r1; p[2][r] = r2; p[3][r] = r3;
      rsum[r] = (r0 + r1) + (r2 + r3);
      m_i[r] = mnew;
    }
    #pragma unroll
    for (int off = 1; off < 16; off <<= 1) {
      #pragma unroll
      for (int r = 0; r < 4; ++r)
        rsum[r] += __shfl_xor(rsum[r], off, 16);
    }
    #pragma unroll
    for (int r = 0; r < 4; ++r) {
      l_i[r] = l_i[r] * alpha[r] + rsum[r];
      acc[0][r] *= alpha[r];
      acc[1][r] *= alpha[r];
      acc[2][r] *= alpha[r];
      acc[3][r] *= alpha[r];
    }

    // P: C-layout -> per-wave LDS slice (no barrier needed)
    #pragma unroll
    for (int ct = 0; ct < 4; ++ct)
      #pragma unroll
      for (int r = 0; r < 4; ++r)
        lds_p[wv][quad * 4 + r][ct * 16 + c] = p[ct][r];

    // LDS -> A-layout frags (row=c, k=half*32+quad*8+j), convert to bf16
    const float* pr = &lds_p[wv][c][quad * 8];
    float4 f0 = *(const float4*)(pr);
    float4 f1 = *(const float4*)(pr + 4);
    float4 f2 = *(const float4*)(pr + 32);
    float4 f3 = *(const float4*)(pr + 36);
    short8 aP0, aP1;
    aP0[0] = (short)f2bf(f0.x); aP0[1] = (short)f2bf(f0.y);
    aP0[2] = (short)f2bf(f0.z); aP0[3] = (short)f2bf(f0.w);
    aP0[4] = (short)f2bf(f1.x); aP0[5] = (short)f2bf(f1.y);
    aP0[6] = (short)f2bf(f1.z); aP0[7] = (short)f2bf(f1.w);
    aP1[0] = (short)f2bf(f2.x); aP1[1] = (short)f2bf(f2.y);
    aP1[2] = (short)f2bf(f2.z); aP1[3] = (short)f2bf(f2.w);
    aP1[4] = (short)f2bf(f3.x); aP1[5] = (short)f2bf(f3.y);
    aP1[6] = (short)f2bf(f3.z); aP1[7] = (short)f2bf(f3.w);

    // PV: 4 d-tiles x 2 k-halves = 8 MFMAs
    #pragma unroll
    for (int d = 0; d < 4; ++d) {
      const unsigned short* vrow = Vb + (size_t)(d * 16 + c) * S_ + kp0;
      short8 bV0 = *(const short8*)(vrow + quad * 8);
      short8 bV1 = *(const short8*)(vrow + 32 + quad * 8);
      acc[d] = __builtin_amdgcn_mfma_f32_16x16x32_bf16(aP0, bV0, acc[d], 0, 0, 0);
      acc[d] = __builtin_amdgcn_mfma_f32_16x16x32_bf16(aP1, bV1, acc[d], 0, 0, 0);
    }
  }

  float inv[4];
  #pragma unroll
  for (int r = 0; r < 4; ++r) inv[r] = 1.f / l_i[r];
  #pragma unroll
  for (int d = 0; d < 4; ++d) {
    #pragma unroll
    for (int r = 0; r < 4; ++r) {
      int srow = q0 + quad * 4 + r;
      ctx[((size_t)(b * S_ + srow)) * D_ + h * HD_ + d * 16 + c] =
          f2bf(acc[d][r] * inv[r]);
    }
  }
}

// ---------------------------------------------------------------------------
// Kernel 3: out-proj + residual. y[m,n] = ctx@Wo.T + bo + x. y stored FP32.
// ---------------------------------------------------------------------------
__global__ __launch_bounds__(256) void out_proj(
    const unsigned short* __restrict__ CTX, const unsigned short* __restrict__ W,
    const float* __restrict__ bo, const float* __restrict__ X,
    float* __restrict__ Y)
{
  const int wv   = threadIdx.x >> 6;
  const int lane = threadIdx.x & 63;
  const int c    = lane & 15;
  const int quad = lane >> 4;
  const int m0   = blockIdx.x * 64 + wv * 16;
  const int n0   = blockIdx.y * 64;

  const unsigned short* arow = CTX + (size_t)(m0 + c) * D_ + quad * 8;
  const unsigned short* brow = W   + (size_t)(n0 + c) * D_ + quad * 8;

  floatx4 acc0 = {0.f,0.f,0.f,0.f}, acc1 = {0.f,0.f,0.f,0.f};
  floatx4 acc2 = {0.f,0.f,0.f,0.f}, acc3 = {0.f,0.f,0.f,0.f};

  for (int k0 = 0; k0 < D_; k0 += 32) {
    short8 a  = *(const short8*)(arow + k0);
    short8 b0 = *(const short8*)(brow + k0);
    short8 b1 = *(const short8*)(brow + 16 * D_ + k0);
    short8 b2 = *(const short8*)(brow + 32 * D_ + k0);
    short8 b3 = *(const short8*)(brow + 48 * D_ + k0);
    acc0 = __builtin_amdgcn_mfma_f32_16x16x32_bf16(a, b0, acc0, 0, 0, 0);
    acc1 = __builtin_amdgcn_mfma_f32_16x16x32_bf16(a, b1, acc1, 0, 0, 0);
    acc2 = __builtin_amdgcn_mfma_f32_16x16x32_bf16(a, b2, acc2, 0, 0, 0);
    acc3 = __builtin_amdgcn_mfma_f32_16x16x32_bf16(a, b3, acc3, 0, 0, 0);
  }

  floatx4 accs[4] = {acc0, acc1, acc2, acc3};
  #pragma unroll
  for (int j = 0; j < 4; ++j) {
    const int n = n0 + j * 16 + c;
    const float bias = bo[n];
    #pragma unroll
    for (int r = 0; r < 4; ++r) {
      const int m = m0 + quad * 4 + r;
      Y[(size_t)m * D_ + n] = accs[j][r] + bias + X[(size_t)m * D_ + n];
    }
  }
}

// ---------------------------------------------------------------------------
// Kernel 4: LayerNorm over last dim (1024). y fp32 in; OUTPUT FP32.
// ---------------------------------------------------------------------------
__global__ __launch_bounds__(256) void ln_kernel(
    const float* __restrict__ Y, const float* __restrict__ gamma,
    const float* __restrict__ beta, float* __restrict__ out)
{
  __shared__ float red[2][4];
  const int row  = blockIdx.x;
  const int tid  = threadIdx.x;
  const int wv   = tid >> 6;
  const int lane = tid & 63;
  const float* y = Y + (size_t)row * D_;

  float v[4];
  float sum = 0.f, sumsq = 0.f;
  #pragma unroll
  for (int i = 0; i < 4; ++i) {
    v[i] = y[tid + i * 256];
    sum += v[i];
    sumsq += v[i] * v[i];
  }
  #pragma unroll
  for (int off = 32; off > 0; off >>= 1) {
    sum   += __shfl_down(sum, off, 64);
    sumsq += __shfl_down(sumsq, off, 64);
  }
  if (lane == 0) { red[0][wv] = sum; red[1][wv] = sumsq; }
  __syncthreads();
  sum   = red[0][0] + red[0][1] + red[0][2] + red[0][3];
  sumsq = red[1][0] + red[1][1] + red[1][2] + red[1][3];

  const float mu   = sum * (1.f / D_);
  const float var  = sumsq * (1.f / D_) - mu * mu;
  const float rstd = rsqrtf(var + 1e-5f);

  #pragma unroll
  for (int i = 0; i < 4; ++i) {
    const int col = tid + i * 256;
    out[(size_t)row * D_ + col] = (v[i] - mu) * rstd * gamma[col] + beta[col];
  }
}

// ---------------------------------------------------------------------------
extern "C" void kernel_launch(void* const* d_in, const int* in_sizes, int n_in,
                              void* d_out, int out_size, void* d_ws, size_t ws_size,
                              hipStream_t stream) {
  const float* x     = (const float*)d_in[0];
  const int*   mask  = (const int*)d_in[1];
  const float* Wq    = (const float*)d_in[2];
  const float* bq    = (const float*)d_in[3];
  const float* Wk    = (const float*)d_in[4];
  const float* bk    = (const float*)d_in[5];
  const float* Wv    = (const float*)d_in[6];
  const float* bv    = (const float*)d_in[7];
  const float* Wo    = (const float*)d_in[8];
  const float* bo    = (const float*)d_in[9];
  const float* gamma = (const float*)d_in[10];
  const float* beta  = (const float*)d_in[11];

  char* ws = (char*)d_ws;
  unsigned short* xb    = (unsigned short*)(ws + WS_XB);
  unsigned short* wqb   = (unsigned short*)(ws + WS_WQ);
  unsigned short* wkb   = (unsigned short*)(ws + WS_WK);
  unsigned short* wvb   = (unsigned short*)(ws + WS_WV);
  unsigned short* wob   = (unsigned short*)(ws + WS_WO);
  unsigned short* q_ws  = (unsigned short*)(ws + WS_Q);
  unsigned short* k_ws  = (unsigned short*)(ws + WS_KK);
  unsigned short* vt_ws = (unsigned short*)(ws + WS_VT);
  float*          y_ws  = (float*)(ws + WS_Y);
  unsigned short* ctx   = (unsigned short*)d_out;

  const int nx4 = (BS_ * D_) / 4;
  const int nw4 = (D_ * D_) / 4;
  cvt_f32_bf16<<<(nx4 + 255) / 256, 256, 0, stream>>>(x,  xb,  nx4);
  cvt_f32_bf16<<<(nw4 + 255) / 256, 256, 0, stream>>>(Wq, wqb, nw4);
  cvt_f32_bf16<<<(nw4 + 255) / 256, 256, 0, stream>>>(Wk, wkb, nw4);
  cvt_f32_bf16<<<(nw4 + 255) / 256, 256, 0, stream>>>(Wv, wvb, nw4);
  cvt_f32_bf16<<<(nw4 + 255) / 256, 256, 0, stream>>>(Wo, wob, nw4);

  proj_qkv<<<dim3(BS_ / 64, D_ / 64, 3), 256, 0, stream>>>(
      xb, wqb, bq, wkb, bk, wvb, bv, q_ws, k_ws, vt_ws);

  attn_kernel<<<dim3(S_ / 64, B_ * H_), 256, 0, stream>>>(
      q_ws, k_ws, vt_ws, mask, ctx);

  out_proj<<<dim3(BS_ / 64, D_ / 64), 256, 0, stream>>>(
      ctx, wob, bo, x, y_ws);

  ln_kernel<<<BS_, 256, 0, stream>>>(y_ws, gamma, beta, (float*)d_out);
}

// Round 8
// 1153.613 us; speedup vs baseline: 1.0034x; 1.0034x over previous
//
#include <hip/hip_runtime.h>

// Problem constants
#define D_  1024
#define S_  2048
#define B_  4
#define H_  16
#define HD_ 64
#define BS_ (B_*S_)   // 8192 rows

typedef __attribute__((ext_vector_type(8))) short short8;   // 8 bf16 = 4 VGPRs
typedef __attribute__((ext_vector_type(4))) float floatx4;  // MFMA C/D

// Workspace layout (byte offsets), 72 MB total.
#define WS_XB ((size_t)0)            // 16 MB bf16 x
#define WS_WQ ((size_t)16 << 20)     // 2 MB bf16 Wq
#define WS_WK ((size_t)18 << 20)
#define WS_WV ((size_t)20 << 20)
#define WS_WO ((size_t)22 << 20)
#define WS_Q  ((size_t)24 << 20)     // 16 MB bf16 Q [b,h,s,hd]
#define WS_KK ((size_t)40 << 20)     // 16 MB bf16 K [b,h,s,hd]
#define WS_VT ((size_t)56 << 20)     // 16 MB bf16 V^T [b,h,hd,s]
#define WS_Y  WS_Q                   // y (fp32, 32 MB) overlays Q+K after attn

static __device__ __forceinline__ unsigned short f2bf(float f) {
  unsigned u = __builtin_bit_cast(unsigned, f);
  unsigned r = (u + 0x7fffu + ((u >> 16) & 1u)) >> 16;  // RNE
  return (unsigned short)r;
}

// ---------------------------------------------------------------------------
// Kernel 0: fp32 -> bf16 convert (RNE), 4 elements per thread.
// ---------------------------------------------------------------------------
__global__ __launch_bounds__(256) void cvt_f32_bf16(
    const float* __restrict__ src, unsigned short* __restrict__ dst, int n4)
{
  int i = blockIdx.x * 256 + threadIdx.x;
  if (i < n4) {
    float4 v = ((const float4*)src)[i];
    ushort4 o;
    o.x = f2bf(v.x); o.y = f2bf(v.y); o.z = f2bf(v.z); o.w = f2bf(v.w);
    ((ushort4*)dst)[i] = o;
  }
}

// ---------------------------------------------------------------------------
// Kernel 1: QKV projection. C[m,n] = sum_k X[m,k]*W[n,k] + b[n]  (x @ W.T + b)
// mode (blockIdx.z): 0->Q [b,h,s,hd]; 1->K [b,h,s,hd]; 2->V^T [b,h,hd,s].
// ---------------------------------------------------------------------------
__global__ __launch_bounds__(256) void proj_qkv(
    const unsigned short* __restrict__ X,
    const unsigned short* __restrict__ Wq, const float* __restrict__ bq,
    const unsigned short* __restrict__ Wk, const float* __restrict__ bk,
    const unsigned short* __restrict__ Wv, const float* __restrict__ bv,
    unsigned short* __restrict__ Qo, unsigned short* __restrict__ Ko,
    unsigned short* __restrict__ Vo)
{
  const int mode = blockIdx.z;
  const unsigned short* W = (mode == 0) ? Wq : ((mode == 1) ? Wk : Wv);
  const float* bias       = (mode == 0) ? bq : ((mode == 1) ? bk : bv);
  unsigned short* dst     = (mode == 0) ? Qo : ((mode == 1) ? Ko : Vo);

  const int wv   = threadIdx.x >> 6;
  const int lane = threadIdx.x & 63;
  const int c    = lane & 15;
  const int quad = lane >> 4;
  const int m0   = blockIdx.x * 64 + wv * 16;
  const int n0   = blockIdx.y * 64;

  const unsigned short* arow = X + (size_t)(m0 + c) * D_ + quad * 8;
  const unsigned short* brow = W + (size_t)(n0 + c) * D_ + quad * 8;

  floatx4 acc0 = {0.f,0.f,0.f,0.f}, acc1 = {0.f,0.f,0.f,0.f};
  floatx4 acc2 = {0.f,0.f,0.f,0.f}, acc3 = {0.f,0.f,0.f,0.f};

  for (int k0 = 0; k0 < D_; k0 += 32) {
    short8 a  = *(const short8*)(arow + k0);
    short8 b0 = *(const short8*)(brow + k0);
    short8 b1 = *(const short8*)(brow + 16 * D_ + k0);
    short8 b2 = *(const short8*)(brow + 32 * D_ + k0);
    short8 b3 = *(const short8*)(brow + 48 * D_ + k0);
    acc0 = __builtin_amdgcn_mfma_f32_16x16x32_bf16(a, b0, acc0, 0, 0, 0);
    acc1 = __builtin_amdgcn_mfma_f32_16x16x32_bf16(a, b1, acc1, 0, 0, 0);
    acc2 = __builtin_amdgcn_mfma_f32_16x16x32_bf16(a, b2, acc2, 0, 0, 0);
    acc3 = __builtin_amdgcn_mfma_f32_16x16x32_bf16(a, b3, acc3, 0, 0, 0);
  }

  const int b  = m0 >> 11;
  const int s0 = m0 & (S_ - 1);
  const int h  = n0 >> 6;

  floatx4 accs[4] = {acc0, acc1, acc2, acc3};
  #pragma unroll
  for (int j = 0; j < 4; ++j) {
    const int n     = n0 + j * 16 + c;
    const float bv_ = bias[n];
    const int hd    = j * 16 + c;
    if (mode < 2) {
      size_t base = ((size_t)((b * H_ + h) * S_ + s0 + quad * 4)) * HD_ + hd;
      #pragma unroll
      for (int r = 0; r < 4; ++r)
        dst[base + (size_t)r * HD_] = f2bf(accs[j][r] + bv_);
    } else {
      size_t base = ((size_t)((b * H_ + h) * HD_ + hd)) * S_ + s0 + quad * 4;
      #pragma unroll
      for (int r = 0; r < 4; ++r)
        dst[base + r] = f2bf(accs[j][r] + bv_);
    }
  }
}

// ---------------------------------------------------------------------------
// Kernel 2 (v3): flash attention, register-pipelined.
// One wave = 16 q-rows; 64-key tiles. Per iter: prefetch NEXT K-frags + mask,
// load CURRENT V-frags at top (consumed after softmax). l_i accumulated via
// 2 MFMAs against an all-ones B (no sum-shuffle). P transits LDS as bf16.
// No barriers (per-wave-private LDS slice).
// ---------------------------------------------------------------------------
__global__ __launch_bounds__(256) void attn_kernel(
    const unsigned short* __restrict__ Q, const unsigned short* __restrict__ K,
    const unsigned short* __restrict__ Vt, const int* __restrict__ mask,
    unsigned short* __restrict__ ctx)
{
  __shared__ unsigned short pbuf[4][16][72];  // per-wave P tile, bf16, 144B rows

  const int wv   = threadIdx.x >> 6;
  const int lane = threadIdx.x & 63;
  const int c    = lane & 15;
  const int quad = lane >> 4;

  const int bh = blockIdx.y;
  const int b  = bh >> 4;
  const int h  = bh & 15;
  const int q0 = blockIdx.x * 64 + wv * 16;

  const unsigned short* Qb = Q  + (size_t)bh * S_ * HD_;
  const unsigned short* Kb = K  + (size_t)bh * S_ * HD_;
  const unsigned short* Vb = Vt + (size_t)bh * HD_ * S_;
  const int* mrow = mask + b * S_;

  short8 aQ0 = *(const short8*)(Qb + (size_t)(q0 + c) * HD_ + quad * 8);
  short8 aQ1 = *(const short8*)(Qb + (size_t)(q0 + c) * HD_ + 32 + quad * 8);

  // bf16 1.0 x8 (for the l-accumulator MFMA)
  short8 ones;
  #pragma unroll
  for (int i = 0; i < 8; ++i) ones[i] = (short)0x3F80;

  float m_i[4] = {-1e30f, -1e30f, -1e30f, -1e30f};
  floatx4 acc[4];
  #pragma unroll
  for (int d = 0; d < 4; ++d) acc[d] = (floatx4){0.f, 0.f, 0.f, 0.f};
  floatx4 accl = {0.f, 0.f, 0.f, 0.f};

  // prime: K-frags + mask for tile 0
  short8 kf[8];
  int mi[4];
  #pragma unroll
  for (int ct = 0; ct < 4; ++ct) {
    const unsigned short* krow = Kb + (size_t)(ct * 16 + c) * HD_;
    kf[2 * ct]     = *(const short8*)(krow + quad * 8);
    kf[2 * ct + 1] = *(const short8*)(krow + 32 + quad * 8);
    mi[ct] = mrow[ct * 16 + c];
  }

  for (int t = 0; t < S_ / 64; ++t) {
    const int kp0    = t * 64;
    const int kp_nxt = (t < S_ / 64 - 1) ? kp0 + 64 : 0;  // wrap: valid addr

    // ---- issue next-tile K + mask, and CURRENT-tile V, up front ----
    short8 nk[8], vf[8];
    int nmi[4];
    #pragma unroll
    for (int ct = 0; ct < 4; ++ct) {
      const unsigned short* krow = Kb + (size_t)(kp_nxt + ct * 16 + c) * HD_;
      nk[2 * ct]     = *(const short8*)(krow + quad * 8);
      nk[2 * ct + 1] = *(const short8*)(krow + 32 + quad * 8);
      const unsigned short* vrow = Vb + (size_t)(ct * 16 + c) * S_ + kp0;
      vf[2 * ct]     = *(const short8*)(vrow + quad * 8);
      vf[2 * ct + 1] = *(const short8*)(vrow + 32 + quad * 8);
      nmi[ct] = mrow[kp_nxt + ct * 16 + c];
    }

    // ---- QK^T with current kf ----
    floatx4 C[4];
    #pragma unroll
    for (int ct = 0; ct < 4; ++ct) {
      floatx4 z = {0.f, 0.f, 0.f, 0.f};
      z = __builtin_amdgcn_mfma_f32_16x16x32_bf16(aQ0, kf[2 * ct],     z, 0, 0, 0);
      z = __builtin_amdgcn_mfma_f32_16x16x32_bf16(aQ1, kf[2 * ct + 1], z, 0, 0, 0);
      C[ct] = z;
    }

    // ---- scores + row-max (16-lane shuffle reduction) ----
    float mb[4];
    #pragma unroll
    for (int ct = 0; ct < 4; ++ct) mb[ct] = (mi[ct] == 0) ? -1e9f : 0.f;

    float s[4][4], tmax[4];
    #pragma unroll
    for (int r = 0; r < 4; ++r) {
      float t0 = C[0][r] * 0.125f + mb[0];
      float t1 = C[1][r] * 0.125f + mb[1];
      float t2 = C[2][r] * 0.125f + mb[2];
      float t3 = C[3][r] * 0.125f + mb[3];
      s[0][r] = t0; s[1][r] = t1; s[2][r] = t2; s[3][r] = t3;
      tmax[r] = fmaxf(fmaxf(t0, t1), fmaxf(t2, t3));
    }
    #pragma unroll
    for (int off = 1; off < 16; off <<= 1) {
      #pragma unroll
      for (int r = 0; r < 4; ++r)
        tmax[r] = fmaxf(tmax[r], __shfl_xor(tmax[r], off, 16));
    }

    // ---- online-softmax rescale (sum handled by ones-MFMA) ----
    float alpha[4];
    #pragma unroll
    for (int r = 0; r < 4; ++r) {
      const float mnew = fmaxf(m_i[r], tmax[r]);
      alpha[r] = __expf(m_i[r] - mnew);
      m_i[r] = mnew;
    }
    unsigned short pb[4][4];
    #pragma unroll
    for (int ct = 0; ct < 4; ++ct)
      #pragma unroll
      for (int r = 0; r < 4; ++r)
        pb[ct][r] = f2bf(__expf(s[ct][r] - m_i[r]));
    #pragma unroll
    for (int r = 0; r < 4; ++r) {
      acc[0][r] *= alpha[r];
      acc[1][r] *= alpha[r];
      acc[2][r] *= alpha[r];
      acc[3][r] *= alpha[r];
      accl[r]   *= alpha[r];
    }

    // ---- P (bf16, C-layout) -> per-wave LDS -> A-layout frags ----
    #pragma unroll
    for (int ct = 0; ct < 4; ++ct)
      #pragma unroll
      for (int r = 0; r < 4; ++r)
        pbuf[wv][quad * 4 + r][ct * 16 + c] = pb[ct][r];

    short8 aP0 = *(const short8*)&pbuf[wv][c][quad * 8];       // keys 0..31
    short8 aP1 = *(const short8*)&pbuf[wv][c][32 + quad * 8];  // keys 32..63

    // ---- PV + l-accumulation ----
    #pragma unroll
    for (int d = 0; d < 4; ++d) {
      acc[d] = __builtin_amdgcn_mfma_f32_16x16x32_bf16(aP0, vf[2 * d],     acc[d], 0, 0, 0);
      acc[d] = __builtin_amdgcn_mfma_f32_16x16x32_bf16(aP1, vf[2 * d + 1], acc[d], 0, 0, 0);
    }
    accl = __builtin_amdgcn_mfma_f32_16x16x32_bf16(aP0, ones, accl, 0, 0, 0);
    accl = __builtin_amdgcn_mfma_f32_16x16x32_bf16(aP1, ones, accl, 0, 0, 0);

    // ---- rotate pipeline ----
    #pragma unroll
    for (int i = 0; i < 8; ++i) kf[i] = nk[i];
    #pragma unroll
    for (int i = 0; i < 4; ++i) mi[i] = nmi[i];
  }

  float inv[4];
  #pragma unroll
  for (int r = 0; r < 4; ++r) inv[r] = 1.f / accl[r];
  #pragma unroll
  for (int d = 0; d < 4; ++d) {
    #pragma unroll
    for (int r = 0; r < 4; ++r) {
      int srow = q0 + quad * 4 + r;
      ctx[((size_t)(b * S_ + srow)) * D_ + h * HD_ + d * 16 + c] =
          f2bf(acc[d][r] * inv[r]);
    }
  }
}

// ---------------------------------------------------------------------------
// Kernel 3: out-proj + residual. y[m,n] = ctx@Wo.T + bo + x. y stored FP32.
// ---------------------------------------------------------------------------
__global__ __launch_bounds__(256) void out_proj(
    const unsigned short* __restrict__ CTX, const unsigned short* __restrict__ W,
    const float* __restrict__ bo, const float* __restrict__ X,
    float* __restrict__ Y)
{
  const int wv   = threadIdx.x >> 6;
  const int lane = threadIdx.x & 63;
  const int c    = lane & 15;
  const int quad = lane >> 4;
  const int m0   = blockIdx.x * 64 + wv * 16;
  const int n0   = blockIdx.y * 64;

  const unsigned short* arow = CTX + (size_t)(m0 + c) * D_ + quad * 8;
  const unsigned short* brow = W   + (size_t)(n0 + c) * D_ + quad * 8;

  floatx4 acc0 = {0.f,0.f,0.f,0.f}, acc1 = {0.f,0.f,0.f,0.f};
  floatx4 acc2 = {0.f,0.f,0.f,0.f}, acc3 = {0.f,0.f,0.f,0.f};

  for (int k0 = 0; k0 < D_; k0 += 32) {
    short8 a  = *(const short8*)(arow + k0);
    short8 b0 = *(const short8*)(brow + k0);
    short8 b1 = *(const short8*)(brow + 16 * D_ + k0);
    short8 b2 = *(const short8*)(brow + 32 * D_ + k0);
    short8 b3 = *(const short8*)(brow + 48 * D_ + k0);
    acc0 = __builtin_amdgcn_mfma_f32_16x16x32_bf16(a, b0, acc0, 0, 0, 0);
    acc1 = __builtin_amdgcn_mfma_f32_16x16x32_bf16(a, b1, acc1, 0, 0, 0);
    acc2 = __builtin_amdgcn_mfma_f32_16x16x32_bf16(a, b2, acc2, 0, 0, 0);
    acc3 = __builtin_amdgcn_mfma_f32_16x16x32_bf16(a, b3, acc3, 0, 0, 0);
  }

  floatx4 accs[4] = {acc0, acc1, acc2, acc3};
  #pragma unroll
  for (int j = 0; j < 4; ++j) {
    const int n = n0 + j * 16 + c;
    const float bias = bo[n];
    #pragma unroll
    for (int r = 0; r < 4; ++r) {
      const int m = m0 + quad * 4 + r;
      Y[(size_t)m * D_ + n] = accs[j][r] + bias + X[(size_t)m * D_ + n];
    }
  }
}

// ---------------------------------------------------------------------------
// Kernel 4: LayerNorm over last dim (1024). y fp32 in; OUTPUT FP32.
// ---------------------------------------------------------------------------
__global__ __launch_bounds__(256) void ln_kernel(
    const float* __restrict__ Y, const float* __restrict__ gamma,
    const float* __restrict__ beta, float* __restrict__ out)
{
  __shared__ float red[2][4];
  const int row  = blockIdx.x;
  const int tid  = threadIdx.x;
  const int wv   = tid >> 6;
  const int lane = tid & 63;
  const float* y = Y + (size_t)row * D_;

  float v[4];
  float sum = 0.f, sumsq = 0.f;
  #pragma unroll
  for (int i = 0; i < 4; ++i) {
    v[i] = y[tid + i * 256];
    sum += v[i];
    sumsq += v[i] * v[i];
  }
  #pragma unroll
  for (int off = 32; off > 0; off >>= 1) {
    sum   += __shfl_down(sum, off, 64);
    sumsq += __shfl_down(sumsq, off, 64);
  }
  if (lane == 0) { red[0][wv] = sum; red[1][wv] = sumsq; }
  __syncthreads();
  sum   = red[0][0] + red[0][1] + red[0][2] + red[0][3];
  sumsq = red[1][0] + red[1][1] + red[1][2] + red[1][3];

  const float mu   = sum * (1.f / D_);
  const float var  = sumsq * (1.f / D_) - mu * mu;
  const float rstd = rsqrtf(var + 1e-5f);

  #pragma unroll
  for (int i = 0; i < 4; ++i) {
    const int col = tid + i * 256;
    out[(size_t)row * D_ + col] = (v[i] - mu) * rstd * gamma[col] + beta[col];
  }
}

// ---------------------------------------------------------------------------
extern "C" void kernel_launch(void* const* d_in, const int* in_sizes, int n_in,
                              void* d_out, int out_size, void* d_ws, size_t ws_size,
                              hipStream_t stream) {
  const float* x     = (const float*)d_in[0];
  const int*   mask  = (const int*)d_in[1];
  const float* Wq    = (const float*)d_in[2];
  const float* bq    = (const float*)d_in[3];
  const float* Wk    = (const float*)d_in[4];
  const float* bk    = (const float*)d_in[5];
  const float* Wv    = (const float*)d_in[6];
  const float* bv    = (const float*)d_in[7];
  const float* Wo    = (const float*)d_in[8];
  const float* bo    = (const float*)d_in[9];
  const float* gamma = (const float*)d_in[10];
  const float* beta  = (const float*)d_in[11];

  char* ws = (char*)d_ws;
  unsigned short* xb    = (unsigned short*)(ws + WS_XB);
  unsigned short* wqb   = (unsigned short*)(ws + WS_WQ);
  unsigned short* wkb   = (unsigned short*)(ws + WS_WK);
  unsigned short* wvb   = (unsigned short*)(ws + WS_WV);
  unsigned short* wob   = (unsigned short*)(ws + WS_WO);
  unsigned short* q_ws  = (unsigned short*)(ws + WS_Q);
  unsigned short* k_ws  = (unsigned short*)(ws + WS_KK);
  unsigned short* vt_ws = (unsigned short*)(ws + WS_VT);
  float*          y_ws  = (float*)(ws + WS_Y);
  unsigned short* ctx   = (unsigned short*)d_out;

  const int nx4 = (BS_ * D_) / 4;
  const int nw4 = (D_ * D_) / 4;
  cvt_f32_bf16<<<(nx4 + 255) / 256, 256, 0, stream>>>(x,  xb,  nx4);
  cvt_f32_bf16<<<(nw4 + 255) / 256, 256, 0, stream>>>(Wq, wqb, nw4);
  cvt_f32_bf16<<<(nw4 + 255) / 256, 256, 0, stream>>>(Wk, wkb, nw4);
  cvt_f32_bf16<<<(nw4 + 255) / 256, 256, 0, stream>>>(Wv, wvb, nw4);
  cvt_f32_bf16<<<(nw4 + 255) / 256, 256, 0, stream>>>(Wo, wob, nw4);

  proj_qkv<<<dim3(BS_ / 64, D_ / 64, 3), 256, 0, stream>>>(
      xb, wqb, bq, wkb, bk, wvb, bv, q_ws, k_ws, vt_ws);

  attn_kernel<<<dim3(S_ / 64, B_ * H_), 256, 0, stream>>>(
      q_ws, k_ws, vt_ws, mask, ctx);

  out_proj<<<dim3(BS_ / 64, D_ / 64), 256, 0, stream>>>(
      ctx, wob, bo, x, y_ws);

  ln_kernel<<<BS_, 256, 0, stream>>>(y_ws, gamma, beta, (float*)d_out);
}

// Round 9
// 928.454 us; speedup vs baseline: 1.2467x; 1.2425x over previous
//
#include <hip/hip_runtime.h>

// Problem constants
#define D_  1024
#define S_  2048
#define B_  4
#define H_  16
#define HD_ 64
#define BS_ (B_*S_)   // 8192 rows

typedef __attribute__((ext_vector_type(8))) short short8;   // 8 bf16 = 4 VGPRs
typedef __attribute__((ext_vector_type(4))) float floatx4;  // MFMA C/D

// Workspace layout (byte offsets), 72 MB total.
#define WS_XB ((size_t)0)            // 16 MB bf16 x
#define WS_WQ ((size_t)16 << 20)     // 2 MB bf16 Wq
#define WS_WK ((size_t)18 << 20)
#define WS_WV ((size_t)20 << 20)
#define WS_WO ((size_t)22 << 20)
#define WS_Q  ((size_t)24 << 20)     // 16 MB bf16 Q [b,h,s,hd]
#define WS_KK ((size_t)40 << 20)     // 16 MB bf16 K [b,h,s,hd]
#define WS_VT ((size_t)56 << 20)     // 16 MB bf16 V^T [b,h,hd,s]
#define WS_Y  WS_Q                   // y (fp32, 32 MB) overlays Q+K after attn

static __device__ __forceinline__ unsigned short f2bf(float f) {
  unsigned u = __builtin_bit_cast(unsigned, f);
  unsigned r = (u + 0x7fffu + ((u >> 16) & 1u)) >> 16;  // RNE
  return (unsigned short)r;
}

// ---------------------------------------------------------------------------
// Kernel 0: fp32 -> bf16 convert (RNE), 4 elements per thread.
// ---------------------------------------------------------------------------
__global__ __launch_bounds__(256) void cvt_f32_bf16(
    const float* __restrict__ src, unsigned short* __restrict__ dst, int n4)
{
  int i = blockIdx.x * 256 + threadIdx.x;
  if (i < n4) {
    float4 v = ((const float4*)src)[i];
    ushort4 o;
    o.x = f2bf(v.x); o.y = f2bf(v.y); o.z = f2bf(v.z); o.w = f2bf(v.w);
    ((ushort4*)dst)[i] = o;
  }
}

// ---------------------------------------------------------------------------
// Kernel 1: QKV projection. C[m,n] = sum_k X[m,k]*W[n,k] + b[n]  (x @ W.T + b)
// mode (blockIdx.z): 0->Q [b,h,s,hd]; 1->K [b,h,s,hd]; 2->V^T [b,h,hd,s].
// ---------------------------------------------------------------------------
__global__ __launch_bounds__(256) void proj_qkv(
    const unsigned short* __restrict__ X,
    const unsigned short* __restrict__ Wq, const float* __restrict__ bq,
    const unsigned short* __restrict__ Wk, const float* __restrict__ bk,
    const unsigned short* __restrict__ Wv, const float* __restrict__ bv,
    unsigned short* __restrict__ Qo, unsigned short* __restrict__ Ko,
    unsigned short* __restrict__ Vo)
{
  const int mode = blockIdx.z;
  const unsigned short* W = (mode == 0) ? Wq : ((mode == 1) ? Wk : Wv);
  const float* bias       = (mode == 0) ? bq : ((mode == 1) ? bk : bv);
  unsigned short* dst     = (mode == 0) ? Qo : ((mode == 1) ? Ko : Vo);

  const int wv   = threadIdx.x >> 6;
  const int lane = threadIdx.x & 63;
  const int c    = lane & 15;
  const int quad = lane >> 4;
  const int m0   = blockIdx.x * 64 + wv * 16;
  const int n0   = blockIdx.y * 64;

  const unsigned short* arow = X + (size_t)(m0 + c) * D_ + quad * 8;
  const unsigned short* brow = W + (size_t)(n0 + c) * D_ + quad * 8;

  floatx4 acc0 = {0.f,0.f,0.f,0.f}, acc1 = {0.f,0.f,0.f,0.f};
  floatx4 acc2 = {0.f,0.f,0.f,0.f}, acc3 = {0.f,0.f,0.f,0.f};

  for (int k0 = 0; k0 < D_; k0 += 32) {
    short8 a  = *(const short8*)(arow + k0);
    short8 b0 = *(const short8*)(brow + k0);
    short8 b1 = *(const short8*)(brow + 16 * D_ + k0);
    short8 b2 = *(const short8*)(brow + 32 * D_ + k0);
    short8 b3 = *(const short8*)(brow + 48 * D_ + k0);
    acc0 = __builtin_amdgcn_mfma_f32_16x16x32_bf16(a, b0, acc0, 0, 0, 0);
    acc1 = __builtin_amdgcn_mfma_f32_16x16x32_bf16(a, b1, acc1, 0, 0, 0);
    acc2 = __builtin_amdgcn_mfma_f32_16x16x32_bf16(a, b2, acc2, 0, 0, 0);
    acc3 = __builtin_amdgcn_mfma_f32_16x16x32_bf16(a, b3, acc3, 0, 0, 0);
  }

  const int b  = m0 >> 11;
  const int s0 = m0 & (S_ - 1);
  const int h  = n0 >> 6;

  floatx4 accs[4] = {acc0, acc1, acc2, acc3};
  #pragma unroll
  for (int j = 0; j < 4; ++j) {
    const int n     = n0 + j * 16 + c;
    const float bv_ = bias[n];
    const int hd    = j * 16 + c;
    if (mode < 2) {
      size_t base = ((size_t)((b * H_ + h) * S_ + s0 + quad * 4)) * HD_ + hd;
      #pragma unroll
      for (int r = 0; r < 4; ++r)
        dst[base + (size_t)r * HD_] = f2bf(accs[j][r] + bv_);
    } else {
      size_t base = ((size_t)((b * H_ + h) * HD_ + hd)) * S_ + s0 + quad * 4;
      #pragma unroll
      for (int r = 0; r < 4; ++r)
        dst[base + r] = f2bf(accs[j][r] + bv_);
    }
  }
}

// ---------------------------------------------------------------------------
// Kernel 2 (v4): flash attention, XCD-local + 32 q-rows/wave.
// 1-D grid of 1024 blocks: id = (bh%8) + 8*(qt + 16*(bh/8)) so all 16 q-tiles
// of one bh land on the same XCD (id%8 heuristic) -> K/V stay L2-resident.
// One wave = TWO 16-row q-subtiles sharing every K/V fragment (halves K/V
// per-row traffic). l_i via ones-MFMA; P transits per-wave LDS as bf16.
// ---------------------------------------------------------------------------
__global__ __launch_bounds__(256) void attn_kernel(
    const unsigned short* __restrict__ Q, const unsigned short* __restrict__ K,
    const unsigned short* __restrict__ Vt, const int* __restrict__ mask,
    unsigned short* __restrict__ ctx)
{
  __shared__ unsigned short pbuf[4][2][16][72];  // [wave][subtile][row][col]

  const int wv   = threadIdx.x >> 6;
  const int lane = threadIdx.x & 63;
  const int c    = lane & 15;
  const int quad = lane >> 4;

  const int id = blockIdx.x;
  const int bh = (id & 7) + 8 * (id >> 7);   // bh%8 == id%8 (XCD co-location)
  const int qt = (id >> 3) & 15;
  const int b  = bh >> 4;
  const int h  = bh & 15;
  const int q0 = qt * 128 + wv * 32;         // 32 q-rows per wave

  const unsigned short* Qb = Q  + (size_t)bh * S_ * HD_;
  const unsigned short* Kb = K  + (size_t)bh * S_ * HD_;
  const unsigned short* Vb = Vt + (size_t)bh * HD_ * S_;
  const int* mrow = mask + b * S_;

  short8 aQ[2][2];
  #pragma unroll
  for (int s = 0; s < 2; ++s) {
    const unsigned short* qrow = Qb + (size_t)(q0 + s * 16 + c) * HD_;
    aQ[s][0] = *(const short8*)(qrow + quad * 8);
    aQ[s][1] = *(const short8*)(qrow + 32 + quad * 8);
  }

  short8 ones;
  #pragma unroll
  for (int i = 0; i < 8; ++i) ones[i] = (short)0x3F80;  // bf16 1.0

  float m_i[2][4];
  floatx4 acc[2][4], accl[2];
  #pragma unroll
  for (int s = 0; s < 2; ++s) {
    #pragma unroll
    for (int r = 0; r < 4; ++r) m_i[s][r] = -1e30f;
    #pragma unroll
    for (int d = 0; d < 4; ++d) acc[s][d] = (floatx4){0.f, 0.f, 0.f, 0.f};
    accl[s] = (floatx4){0.f, 0.f, 0.f, 0.f};
  }

  for (int t = 0; t < S_ / 64; ++t) {
    const int kp0 = t * 64;

    float mb[4];
    #pragma unroll
    for (int ct = 0; ct < 4; ++ct)
      mb[ct] = (mrow[kp0 + ct * 16 + c] == 0) ? -1e9f : 0.f;

    // ---- QK^T: K frags shared by both q-subtiles ----
    floatx4 C[2][4];
    #pragma unroll
    for (int ct = 0; ct < 4; ++ct) {
      const unsigned short* krow = Kb + (size_t)(kp0 + ct * 16 + c) * HD_;
      short8 k0 = *(const short8*)(krow + quad * 8);
      short8 k1 = *(const short8*)(krow + 32 + quad * 8);
      floatx4 z0 = {0.f,0.f,0.f,0.f}, z1 = {0.f,0.f,0.f,0.f};
      z0 = __builtin_amdgcn_mfma_f32_16x16x32_bf16(aQ[0][0], k0, z0, 0, 0, 0);
      z1 = __builtin_amdgcn_mfma_f32_16x16x32_bf16(aQ[1][0], k0, z1, 0, 0, 0);
      z0 = __builtin_amdgcn_mfma_f32_16x16x32_bf16(aQ[0][1], k1, z0, 0, 0, 0);
      z1 = __builtin_amdgcn_mfma_f32_16x16x32_bf16(aQ[1][1], k1, z1, 0, 0, 0);
      C[0][ct] = z0;
      C[1][ct] = z1;
    }

    // ---- softmax per subtile (sum via ones-MFMA later) ----
    #pragma unroll
    for (int s = 0; s < 2; ++s) {
      float sc[4][4], tmax[4];
      #pragma unroll
      for (int r = 0; r < 4; ++r) {
        float t0 = C[s][0][r] * 0.125f + mb[0];
        float t1 = C[s][1][r] * 0.125f + mb[1];
        float t2 = C[s][2][r] * 0.125f + mb[2];
        float t3 = C[s][3][r] * 0.125f + mb[3];
        sc[0][r] = t0; sc[1][r] = t1; sc[2][r] = t2; sc[3][r] = t3;
        tmax[r] = fmaxf(fmaxf(t0, t1), fmaxf(t2, t3));
      }
      #pragma unroll
      for (int off = 1; off < 16; off <<= 1) {
        #pragma unroll
        for (int r = 0; r < 4; ++r)
          tmax[r] = fmaxf(tmax[r], __shfl_xor(tmax[r], off, 16));
      }
      float alpha[4];
      #pragma unroll
      for (int r = 0; r < 4; ++r) {
        const float mnew = fmaxf(m_i[s][r], tmax[r]);
        alpha[r] = __expf(m_i[s][r] - mnew);
        m_i[s][r] = mnew;
      }
      #pragma unroll
      for (int ct = 0; ct < 4; ++ct)
        #pragma unroll
        for (int r = 0; r < 4; ++r)
          pbuf[wv][s][quad * 4 + r][ct * 16 + c] =
              f2bf(__expf(sc[ct][r] - m_i[s][r]));
      #pragma unroll
      for (int r = 0; r < 4; ++r) {
        acc[s][0][r] *= alpha[r];
        acc[s][1][r] *= alpha[r];
        acc[s][2][r] *= alpha[r];
        acc[s][3][r] *= alpha[r];
        accl[s][r]   *= alpha[r];
      }
    }

    // ---- P A-frags from per-wave LDS ----
    short8 aP[2][2];
    #pragma unroll
    for (int s = 0; s < 2; ++s) {
      aP[s][0] = *(const short8*)&pbuf[wv][s][c][quad * 8];
      aP[s][1] = *(const short8*)&pbuf[wv][s][c][32 + quad * 8];
    }

    // ---- PV: V frags shared by both q-subtiles ----
    #pragma unroll
    for (int d = 0; d < 4; ++d) {
      const unsigned short* vrow = Vb + (size_t)(d * 16 + c) * S_ + kp0;
      short8 v0 = *(const short8*)(vrow + quad * 8);
      short8 v1 = *(const short8*)(vrow + 32 + quad * 8);
      acc[0][d] = __builtin_amdgcn_mfma_f32_16x16x32_bf16(aP[0][0], v0, acc[0][d], 0, 0, 0);
      acc[1][d] = __builtin_amdgcn_mfma_f32_16x16x32_bf16(aP[1][0], v0, acc[1][d], 0, 0, 0);
      acc[0][d] = __builtin_amdgcn_mfma_f32_16x16x32_bf16(aP[0][1], v1, acc[0][d], 0, 0, 0);
      acc[1][d] = __builtin_amdgcn_mfma_f32_16x16x32_bf16(aP[1][1], v1, acc[1][d], 0, 0, 0);
    }
    #pragma unroll
    for (int s = 0; s < 2; ++s) {
      accl[s] = __builtin_amdgcn_mfma_f32_16x16x32_bf16(aP[s][0], ones, accl[s], 0, 0, 0);
      accl[s] = __builtin_amdgcn_mfma_f32_16x16x32_bf16(aP[s][1], ones, accl[s], 0, 0, 0);
    }
  }

  // epilogue
  #pragma unroll
  for (int s = 0; s < 2; ++s) {
    float inv[4];
    #pragma unroll
    for (int r = 0; r < 4; ++r) inv[r] = 1.f / accl[s][r];
    #pragma unroll
    for (int d = 0; d < 4; ++d) {
      #pragma unroll
      for (int r = 0; r < 4; ++r) {
        int srow = q0 + s * 16 + quad * 4 + r;
        ctx[((size_t)(b * S_ + srow)) * D_ + h * HD_ + d * 16 + c] =
            f2bf(acc[s][d][r] * inv[r]);
      }
    }
  }
}

// ---------------------------------------------------------------------------
// Kernel 3: out-proj + residual. y[m,n] = ctx@Wo.T + bo + x. y stored FP32.
// ---------------------------------------------------------------------------
__global__ __launch_bounds__(256) void out_proj(
    const unsigned short* __restrict__ CTX, const unsigned short* __restrict__ W,
    const float* __restrict__ bo, const float* __restrict__ X,
    float* __restrict__ Y)
{
  const int wv   = threadIdx.x >> 6;
  const int lane = threadIdx.x & 63;
  const int c    = lane & 15;
  const int quad = lane >> 4;
  const int m0   = blockIdx.x * 64 + wv * 16;
  const int n0   = blockIdx.y * 64;

  const unsigned short* arow = CTX + (size_t)(m0 + c) * D_ + quad * 8;
  const unsigned short* brow = W   + (size_t)(n0 + c) * D_ + quad * 8;

  floatx4 acc0 = {0.f,0.f,0.f,0.f}, acc1 = {0.f,0.f,0.f,0.f};
  floatx4 acc2 = {0.f,0.f,0.f,0.f}, acc3 = {0.f,0.f,0.f,0.f};

  for (int k0 = 0; k0 < D_; k0 += 32) {
    short8 a  = *(const short8*)(arow + k0);
    short8 b0 = *(const short8*)(brow + k0);
    short8 b1 = *(const short8*)(brow + 16 * D_ + k0);
    short8 b2 = *(const short8*)(brow + 32 * D_ + k0);
    short8 b3 = *(const short8*)(brow + 48 * D_ + k0);
    acc0 = __builtin_amdgcn_mfma_f32_16x16x32_bf16(a, b0, acc0, 0, 0, 0);
    acc1 = __builtin_amdgcn_mfma_f32_16x16x32_bf16(a, b1, acc1, 0, 0, 0);
    acc2 = __builtin_amdgcn_mfma_f32_16x16x32_bf16(a, b2, acc2, 0, 0, 0);
    acc3 = __builtin_amdgcn_mfma_f32_16x16x32_bf16(a, b3, acc3, 0, 0, 0);
  }

  floatx4 accs[4] = {acc0, acc1, acc2, acc3};
  #pragma unroll
  for (int j = 0; j < 4; ++j) {
    const int n = n0 + j * 16 + c;
    const float bias = bo[n];
    #pragma unroll
    for (int r = 0; r < 4; ++r) {
      const int m = m0 + quad * 4 + r;
      Y[(size_t)m * D_ + n] = accs[j][r] + bias + X[(size_t)m * D_ + n];
    }
  }
}

// ---------------------------------------------------------------------------
// Kernel 4: LayerNorm over last dim (1024). y fp32 in; OUTPUT FP32.
// ---------------------------------------------------------------------------
__global__ __launch_bounds__(256) void ln_kernel(
    const float* __restrict__ Y, const float* __restrict__ gamma,
    const float* __restrict__ beta, float* __restrict__ out)
{
  __shared__ float red[2][4];
  const int row  = blockIdx.x;
  const int tid  = threadIdx.x;
  const int wv   = tid >> 6;
  const int lane = tid & 63;
  const float* y = Y + (size_t)row * D_;

  float v[4];
  float sum = 0.f, sumsq = 0.f;
  #pragma unroll
  for (int i = 0; i < 4; ++i) {
    v[i] = y[tid + i * 256];
    sum += v[i];
    sumsq += v[i] * v[i];
  }
  #pragma unroll
  for (int off = 32; off > 0; off >>= 1) {
    sum   += __shfl_down(sum, off, 64);
    sumsq += __shfl_down(sumsq, off, 64);
  }
  if (lane == 0) { red[0][wv] = sum; red[1][wv] = sumsq; }
  __syncthreads();
  sum   = red[0][0] + red[0][1] + red[0][2] + red[0][3];
  sumsq = red[1][0] + red[1][1] + red[1][2] + red[1][3];

  const float mu   = sum * (1.f / D_);
  const float var  = sumsq * (1.f / D_) - mu * mu;
  const float rstd = rsqrtf(var + 1e-5f);

  #pragma unroll
  for (int i = 0; i < 4; ++i) {
    const int col = tid + i * 256;
    out[(size_t)row * D_ + col] = (v[i] - mu) * rstd * gamma[col] + beta[col];
  }
}

// ---------------------------------------------------------------------------
extern "C" void kernel_launch(void* const* d_in, const int* in_sizes, int n_in,
                              void* d_out, int out_size, void* d_ws, size_t ws_size,
                              hipStream_t stream) {
  const float* x     = (const float*)d_in[0];
  const int*   mask  = (const int*)d_in[1];
  const float* Wq    = (const float*)d_in[2];
  const float* bq    = (const float*)d_in[3];
  const float* Wk    = (const float*)d_in[4];
  const float* bk    = (const float*)d_in[5];
  const float* Wv    = (const float*)d_in[6];
  const float* bv    = (const float*)d_in[7];
  const float* Wo    = (const float*)d_in[8];
  const float* bo    = (const float*)d_in[9];
  const float* gamma = (const float*)d_in[10];
  const float* beta  = (const float*)d_in[11];

  char* ws = (char*)d_ws;
  unsigned short* xb    = (unsigned short*)(ws + WS_XB);
  unsigned short* wqb   = (unsigned short*)(ws + WS_WQ);
  unsigned short* wkb   = (unsigned short*)(ws + WS_WK);
  unsigned short* wvb   = (unsigned short*)(ws + WS_WV);
  unsigned short* wob   = (unsigned short*)(ws + WS_WO);
  unsigned short* q_ws  = (unsigned short*)(ws + WS_Q);
  unsigned short* k_ws  = (unsigned short*)(ws + WS_KK);
  unsigned short* vt_ws = (unsigned short*)(ws + WS_VT);
  float*          y_ws  = (float*)(ws + WS_Y);
  unsigned short* ctx   = (unsigned short*)d_out;

  const int nx4 = (BS_ * D_) / 4;
  const int nw4 = (D_ * D_) / 4;
  cvt_f32_bf16<<<(nx4 + 255) / 256, 256, 0, stream>>>(x,  xb,  nx4);
  cvt_f32_bf16<<<(nw4 + 255) / 256, 256, 0, stream>>>(Wq, wqb, nw4);
  cvt_f32_bf16<<<(nw4 + 255) / 256, 256, 0, stream>>>(Wk, wkb, nw4);
  cvt_f32_bf16<<<(nw4 + 255) / 256, 256, 0, stream>>>(Wv, wvb, nw4);
  cvt_f32_bf16<<<(nw4 + 255) / 256, 256, 0, stream>>>(Wo, wob, nw4);

  proj_qkv<<<dim3(BS_ / 64, D_ / 64, 3), 256, 0, stream>>>(
      xb, wqb, bq, wkb, bk, wvb, bv, q_ws, k_ws, vt_ws);

  attn_kernel<<<dim3(16 * 64), 256, 0, stream>>>(   // 1024 blocks, swizzled
      q_ws, k_ws, vt_ws, mask, ctx);

  out_proj<<<dim3(BS_ / 64, D_ / 64), 256, 0, stream>>>(
      ctx, wob, bo, x, y_ws);

  ln_kernel<<<BS_, 256, 0, stream>>>(y_ws, gamma, beta, (float*)d_out);
}